// Round 1
// baseline (57673.932 us; speedup 1.0000x reference)
//
#include <hip/hip_runtime.h>
#include <cstddef>

// Problem constants
constexpr int B_ = 512, T_ = 128, Z_ = 128, HE_ = 512, HD_ = 2048, NOUT_ = 123;

// Workspace layout (in floats)
constexpr size_t OFF_HF   = 0;
constexpr size_t OFF_CF   = OFF_HF + (size_t)B_*HE_;
constexpr size_t OFF_HB   = OFF_CF + (size_t)B_*HE_;
constexpr size_t OFF_CB   = OFF_HB + (size_t)B_*HE_;
constexpr size_t OFF_HD   = OFF_CB + (size_t)B_*HE_;        // 512x2048
constexpr size_t OFF_CD   = OFF_HD + (size_t)B_*HD_;
constexpr size_t OFF_ZW   = OFF_CD + (size_t)B_*HD_;        // 512x8192
constexpr size_t OFF_G    = OFF_ZW + (size_t)B_*4*HD_;      // 512x8192 scratch (also enc g, init g)
constexpr size_t OFF_HN   = OFF_G  + (size_t)B_*4*HD_;      // 512x1024
constexpr size_t OFF_ZMZL = OFF_HN + (size_t)B_*2*HE_;      // 512x256
constexpr size_t OFF_Z    = OFF_ZMZL + (size_t)B_*2*Z_;     // 512x128
constexpr size_t OFF_WX   = OFF_Z + (size_t)B_*Z_;          // 2x8192
constexpr size_t OFF_HS   = OFF_WX + (size_t)2*4*HD_;       // optional 512x128x2048
constexpr size_t BASE_FLOATS = OFF_HS;
constexpr size_t HS_FLOATS = (size_t)B_*T_*HD_;

__device__ __forceinline__ float sigm(float x) { return 1.f / (1.f + expf(-x)); }

// ---------------- Generic tiled GEMM:  C[m,n] = sum_k A[m*lda+aoff+k] * W[n*ldw+woff+k] (+bias[n])
// BM=BN=64, BK=16, 256 threads, 4x4 micro-tile. M must be multiple of 64; N guarded.
__device__ __forceinline__ void gemm_body(
    const float* __restrict__ A, const float* __restrict__ W,
    const float* __restrict__ bias, float* __restrict__ C,
    int N, int Kd, int lda, int aoff, int ldw, int woff,
    int ldc, int coff, int m0, int n0)
{
    __shared__ __align__(16) float As[16][68];
    __shared__ __align__(16) float Ws[16][68];
    const int tid = threadIdx.x;
    const int tx = tid & 15, ty = tid >> 4;
    float acc[4][4] = {};
    for (int k0 = 0; k0 < Kd; k0 += 16) {
#pragma unroll
        for (int i = 0; i < 4; ++i) {
            int e = tid + i * 256;
            int mm = e >> 4, kk = e & 15;
            As[kk][mm] = A[(size_t)(m0 + mm) * lda + aoff + k0 + kk];
        }
#pragma unroll
        for (int i = 0; i < 4; ++i) {
            int e = tid + i * 256;
            int nn = e >> 4, kk = e & 15;
            int n = n0 + nn;
            Ws[kk][nn] = (n < N) ? W[(size_t)n * ldw + woff + k0 + kk] : 0.f;
        }
        __syncthreads();
#pragma unroll
        for (int kk = 0; kk < 16; ++kk) {
            float4 a = *reinterpret_cast<const float4*>(&As[kk][ty * 4]);
            float4 w = *reinterpret_cast<const float4*>(&Ws[kk][tx * 4]);
            float av[4] = {a.x, a.y, a.z, a.w};
            float wv[4] = {w.x, w.y, w.z, w.w};
#pragma unroll
            for (int i = 0; i < 4; ++i)
#pragma unroll
                for (int j = 0; j < 4; ++j)
                    acc[i][j] = fmaf(av[i], wv[j], acc[i][j]);
        }
        __syncthreads();
    }
#pragma unroll
    for (int i = 0; i < 4; ++i) {
        int m = m0 + ty * 4 + i;
#pragma unroll
        for (int j = 0; j < 4; ++j) {
            int n = n0 + tx * 4 + j;
            if (n < N) {
                float v = acc[i][j];
                if (bias) v += bias[n];
                C[(size_t)m * ldc + coff + n] = v;
            }
        }
    }
}

__global__ __launch_bounds__(256) void gemm_k(
    const float* __restrict__ A, const float* __restrict__ W,
    const float* __restrict__ bias, float* __restrict__ C,
    int N, int Kd, int lda, int aoff, int ldw, int woff, int ldc, int coff)
{
    gemm_body(A, W, bias, C, N, Kd, lda, aoff, ldw, woff, ldc, coff,
              blockIdx.x * 64, blockIdx.y * 64);
}

// Encoder recurrent GEMM, both directions via blockIdx.z. g layout: [dir][512][2048]
__global__ __launch_bounds__(256) void gemm_enc_k(
    const float* __restrict__ hF, const float* __restrict__ hB,
    const float* __restrict__ Wf, const float* __restrict__ Wb,
    float* __restrict__ g)
{
    const float* A = blockIdx.z ? hB : hF;
    const float* W = blockIdx.z ? Wb : Wf;
    float* C = g + (size_t)blockIdx.z * ((size_t)B_ * 4 * HE_);
    gemm_body(A, W, nullptr, C, 4 * HE_, HE_, HE_, 0, HE_, 0, 4 * HE_, 0,
              blockIdx.x * 64, blockIdx.y * 64);
}

// ---------------- Encoder pointwise gate+state update (both dirs), masked by lengths
__global__ __launch_bounds__(256) void point_enc(
    const float* __restrict__ g, const float* __restrict__ data,
    const float* __restrict__ Wih_f, const float* __restrict__ bf,
    const float* __restrict__ Wih_b, const float* __restrict__ bb,
    const int* __restrict__ lengths,
    float* __restrict__ hF, float* __restrict__ cF,
    float* __restrict__ hB, float* __restrict__ cB, int t)
{
    int idx = blockIdx.x * 256 + threadIdx.x;   // 2*512*512
    int dir = idx >> 18;
    int r = idx & ((1 << 18) - 1);
    int b = r >> 9, n = r & 511;
    int L = lengths[b]; L = L < 1 ? 1 : (L > 128 ? 128 : L);
    if (t >= L) return;  // masked step: h,c unchanged
    const float* gp = g + (size_t)dir * ((size_t)B_ * 4 * HE_) + (size_t)b * (4 * HE_);
    float gi = gp[n], gf = gp[HE_ + n], gg = gp[2 * HE_ + n], go = gp[3 * HE_ + n];
    int row = dir ? (L - 1 - t) : t;            // >=0 since t < L
    float x0 = data[b * 258 + (row + 1) * 2 + 0];
    float x1 = data[b * 258 + (row + 1) * 2 + 1];
    const float* Wih = dir ? Wih_b : Wih_f;
    const float* bias = dir ? bb : bf;
    gi += bias[n]          + x0 * Wih[2 * n]              + x1 * Wih[2 * n + 1];
    gf += bias[HE_ + n]    + x0 * Wih[2 * (HE_ + n)]      + x1 * Wih[2 * (HE_ + n) + 1];
    gg += bias[2*HE_ + n]  + x0 * Wih[2 * (2*HE_ + n)]    + x1 * Wih[2 * (2*HE_ + n) + 1];
    go += bias[3*HE_ + n]  + x0 * Wih[2 * (3*HE_ + n)]    + x1 * Wih[2 * (3*HE_ + n) + 1];
    float* h = dir ? hB : hF;
    float* c = dir ? cB : cF;
    int o = b * HE_ + n;
    float c2 = sigm(gf) * c[o] + sigm(gi) * tanhf(gg);
    float h2 = sigm(go) * tanhf(c2);
    h[o] = h2; c[o] = c2;
}

// ---------------- h_n = concat(hF, hB)
__global__ __launch_bounds__(256) void copy_hn(
    const float* __restrict__ hF, const float* __restrict__ hB, float* __restrict__ hn)
{
    int i = blockIdx.x * 256 + threadIdx.x;   // 512*1024
    int b = i >> 10, j = i & 1023;
    hn[i] = (j < 512) ? hF[b * 512 + j] : hB[b * 512 + j - 512];
}

// ---------------- z = zm + exp(0.5*zl)*eps ; also emit zm, zl outputs
__global__ __launch_bounds__(256) void point_z(
    const float* __restrict__ zmzl, const float* __restrict__ eps,
    float* __restrict__ ozm, float* __restrict__ ozl, float* __restrict__ z)
{
    int i = blockIdx.x * 256 + threadIdx.x;   // 512*128
    int b = i >> 7, j = i & 127;
    float zm = zmzl[b * 256 + j], zl = zmzl[b * 256 + 128 + j];
    ozm[i] = zm; ozl[i] = zl;
    z[i] = zm + expf(0.5f * zl) * eps[i];
}

// ---------------- h0,c0 = split(tanh(init_gemm))
__global__ __launch_bounds__(256) void point_init(
    const float* __restrict__ g, float* __restrict__ h, float* __restrict__ c)
{
    int i = blockIdx.x * 256 + threadIdx.x;   // 512*2048
    int b = i >> 11, n = i & 2047;
    h[i] = tanhf(g[(size_t)b * 4096 + n]);
    c[i] = tanhf(g[(size_t)b * 4096 + 2048 + n]);
}

// ---------------- extract dec_Wih columns 0,1 into contiguous wx
__global__ __launch_bounds__(256) void prep_wx(
    const float* __restrict__ Wih, float* __restrict__ wx)
{
    int j = blockIdx.x * 256 + threadIdx.x;   // 8192
    wx[j] = Wih[(size_t)j * 133];
    wx[8192 + j] = Wih[(size_t)j * 133 + 1];
}

// ---------------- Decoder pointwise gate+state update (full mask)
__global__ __launch_bounds__(256) void point_dec(
    const float* __restrict__ g, const float* __restrict__ zW,
    const float* __restrict__ data, const float* __restrict__ wx,
    float* __restrict__ h, float* __restrict__ c, float* __restrict__ hs, int t)
{
    int idx = blockIdx.x * 256 + threadIdx.x;  // 512*2048
    int b = idx >> 11, n = idx & 2047;
    float x0 = data[b * 258 + t * 2 + 0];
    float x1 = data[b * 258 + t * 2 + 1];
    const float* gp = g + (size_t)b * 8192;
    const float* zp = zW + (size_t)b * 8192;
    int j0 = n, j1 = 2048 + n, j2 = 4096 + n, j3 = 6144 + n;
    float gi = gp[j0] + zp[j0] + x0 * wx[j0] + x1 * wx[8192 + j0];
    float gf = gp[j1] + zp[j1] + x0 * wx[j1] + x1 * wx[8192 + j1];
    float gg = gp[j2] + zp[j2] + x0 * wx[j2] + x1 * wx[8192 + j2];
    float go = gp[j3] + zp[j3] + x0 * wx[j3] + x1 * wx[8192 + j3];
    float c2 = sigm(gf) * c[idx] + sigm(gi) * tanhf(gg);
    float h2 = sigm(go) * tanhf(c2);
    h[idx] = h2; c[idx] = c2;
    if (hs) hs[(size_t)b * (T_ * HD_) + (size_t)t * HD_ + n] = h2;
}

// ---------------- Per-step output projection: params[b,t,:] = h[b,:] @ out_W^T + out_b
__global__ __launch_bounds__(256) void proj_step(
    const float* __restrict__ h, const float* __restrict__ out_W,
    const float* __restrict__ out_b, float* __restrict__ out, int t)
{
    __shared__ __align__(16) float sh[2048];
    int b = blockIdx.x;
    for (int i = threadIdx.x; i < 2048; i += 256) sh[i] = h[(size_t)b * 2048 + i];
    __syncthreads();
    int n = threadIdx.x >> 1, half = threadIdx.x & 1;
    if (n >= NOUT_) return;
    const float4* w4 = reinterpret_cast<const float4*>(out_W + (size_t)n * 2048 + half * 1024);
    const float4* h4 = reinterpret_cast<const float4*>(sh + half * 1024);
    float s = 0.f;
#pragma unroll 4
    for (int k = 0; k < 256; ++k) {
        float4 a = h4[k], w = w4[k];
        s += a.x * w.x + a.y * w.y + a.z * w.z + a.w * w.w;
    }
    s += __shfl_xor(s, 1);
    if (half == 0) out[(size_t)b * (T_ * NOUT_) + (size_t)t * NOUT_ + n] = s + out_b[n];
}

extern "C" void kernel_launch(void* const* d_in, const int* in_sizes, int n_in,
                              void* d_out, int out_size, void* d_ws, size_t ws_size,
                              hipStream_t stream)
{
    const float* data      = (const float*)d_in[0];
    const float* eps       = (const float*)d_in[1];
    const float* enc_Wih_f = (const float*)d_in[2];
    const float* enc_Whh_f = (const float*)d_in[3];
    const float* enc_b_f   = (const float*)d_in[4];
    const float* enc_Wih_b = (const float*)d_in[5];
    const float* enc_Whh_b = (const float*)d_in[6];
    const float* enc_b_b   = (const float*)d_in[7];
    const float* enc_out_W = (const float*)d_in[8];
    const float* enc_out_b = (const float*)d_in[9];
    const float* init_W    = (const float*)d_in[10];
    const float* init_b    = (const float*)d_in[11];
    const float* dec_Wih   = (const float*)d_in[12];
    const float* dec_Whh   = (const float*)d_in[13];
    const float* dec_b     = (const float*)d_in[14];
    const float* out_W     = (const float*)d_in[15];
    const float* out_b     = (const float*)d_in[16];
    const int*   lengths   = (const int*)d_in[17];

    float* ws  = (float*)d_ws;
    float* out = (float*)d_out;
    float* hF = ws + OFF_HF, *cF = ws + OFF_CF, *hB = ws + OFF_HB, *cB = ws + OFF_CB;
    float* hd = ws + OFF_HD, *cd = ws + OFF_CD;
    float* zW = ws + OFF_ZW, *g = ws + OFF_G, *hn = ws + OFF_HN;
    float* zmzl = ws + OFF_ZMZL, *z = ws + OFF_Z, *wx = ws + OFF_WX;
    float* ozm = out + (size_t)B_ * T_ * NOUT_;
    float* ozl = ozm + (size_t)B_ * Z_;

    // zero-init encoder h/c (ws is poisoned 0xAA before every timed call)
    hipMemsetAsync(ws, 0, (size_t)4 * B_ * HE_ * sizeof(float), stream);

    // ---- encoder: 128 steps, both directions fused per launch
    for (int t = 0; t < T_; ++t) {
        gemm_enc_k<<<dim3(8, 32, 2), 256, 0, stream>>>(hF, hB, enc_Whh_f, enc_Whh_b, g);
        point_enc<<<2048, 256, 0, stream>>>(g, data, enc_Wih_f, enc_b_f, enc_Wih_b, enc_b_b,
                                            lengths, hF, cF, hB, cB, t);
    }

    // ---- latent + decoder init
    copy_hn<<<2048, 256, 0, stream>>>(hF, hB, hn);
    gemm_k<<<dim3(8, 4), 256, 0, stream>>>(hn, enc_out_W, enc_out_b, zmzl,
                                           256, 1024, 1024, 0, 1024, 0, 256, 0);
    point_z<<<256, 256, 0, stream>>>(zmzl, eps, ozm, ozl, z);
    gemm_k<<<dim3(8, 64), 256, 0, stream>>>(z, init_W, init_b, g,
                                            4096, 128, 128, 0, 128, 0, 4096, 0);
    point_init<<<4096, 256, 0, stream>>>(g, hd, cd);
    // zW = z @ dec_Wih[:,5:133]^T + dec_b
    gemm_k<<<dim3(8, 128), 256, 0, stream>>>(z, dec_Wih, dec_b, zW,
                                             8192, 128, 128, 0, 133, 5, 8192, 0);
    prep_wx<<<32, 256, 0, stream>>>(dec_Wih, wx);

    // ---- decoder: 128 steps
    bool big = ws_size >= (BASE_FLOATS + HS_FLOATS) * sizeof(float);
    float* hs = big ? (ws + OFF_HS) : nullptr;
    for (int t = 0; t < T_; ++t) {
        gemm_k<<<dim3(8, 128), 256, 0, stream>>>(hd, dec_Whh, nullptr, g,
                                                 8192, 2048, 2048, 0, 2048, 0, 8192, 0);
        point_dec<<<4096, 256, 0, stream>>>(g, zW, data, wx, hd, cd, hs, t);
        if (!big) proj_step<<<512, 256, 0, stream>>>(hd, out_W, out_b, out, t);
    }
    if (big) {
        // params = hs @ out_W^T + out_b  (M=65536, N=123, K=2048)
        gemm_k<<<dim3(1024, 2), 256, 0, stream>>>(hs, out_W, out_b, out,
                                                  123, 2048, 2048, 0, 2048, 0, 123, 0);
    }
}

// Round 2
// 16918.637 us; speedup vs baseline: 3.4089x; 3.4089x over previous
//
#include <hip/hip_runtime.h>
#include <cstddef>
#include <cstdint>

typedef unsigned short u16;

// Problem constants
constexpr int B_ = 512, T_ = 128, Z_ = 128, HE_ = 512, HD_ = 2048, NOUT_ = 123;

// ---------------- Workspace layout ----------------
// fp32 region (offsets in floats)
constexpr size_t OFF_HF   = 0;
constexpr size_t OFF_CF   = OFF_HF + (size_t)B_*HE_;
constexpr size_t OFF_HB   = OFF_CF + (size_t)B_*HE_;
constexpr size_t OFF_CB   = OFF_HB + (size_t)B_*HE_;
constexpr size_t OFF_HD   = OFF_CB + (size_t)B_*HE_;        // 512x2048
constexpr size_t OFF_CD   = OFF_HD + (size_t)B_*HD_;
constexpr size_t OFF_ZW   = OFF_CD + (size_t)B_*HD_;        // 512x8192
constexpr size_t OFF_G    = OFF_ZW + (size_t)B_*4*HD_;      // 512x8192 scratch
constexpr size_t OFF_HN   = OFF_G  + (size_t)B_*4*HD_;      // 512x1024
constexpr size_t OFF_ZMZL = OFF_HN + (size_t)B_*2*HE_;      // 512x256
constexpr size_t OFF_Z    = OFF_ZMZL + (size_t)B_*2*Z_;     // 512x128
constexpr size_t OFF_WX   = OFF_Z + (size_t)B_*Z_;          // 2x8192
constexpr size_t BASE_FLOATS = OFF_WX + (size_t)2*4*HD_;

// bf16 region (offsets in u16, relative to ws + BASE_FLOATS floats)
constexpr size_t SH_WDEC  = 0;                               // 8192x2048
constexpr size_t SH_WENCF = SH_WDEC  + (size_t)4*HD_*HD_;    // 2048x512
constexpr size_t SH_WENCB = SH_WENCF + (size_t)4*HE_*HE_;
constexpr size_t SH_OUTW  = SH_WENCB + (size_t)4*HE_*HE_;    // 128x2048 (padded, rows>=123 zero)
constexpr size_t SH_HDEC  = SH_OUTW  + (size_t)128*HD_;      // 512x2048
constexpr size_t SH_HENCF = SH_HDEC  + (size_t)B_*HD_;       // 512x512
constexpr size_t SH_HENCB = SH_HENCF + (size_t)B_*HE_;       // 512x512 (contiguous with F)
constexpr size_t SH_HS    = SH_HENCB + (size_t)B_*HE_;       // optional 512x128x2048
constexpr size_t HS_SHORTS = (size_t)B_*T_*HD_;

__device__ __forceinline__ float sigm(float x) { return 1.f / (1.f + expf(-x)); }

__device__ __forceinline__ u16 f2bf(float x) {
    union { float f; uint32_t u; } v; v.f = x;
    uint32_t r = v.u + 0x7fffu + ((v.u >> 16) & 1u);
    return (u16)(r >> 16);
}

// ================= bf16 MFMA GEMM: C[m,n] = sum_k A[m,k]*W[n,k] (+bias[n]) =================
// 128x128 block tile, 256 threads (4 waves, 2x2), each wave 64x64 via 4x4 of 16x16x32 MFMA.
// BK=32. LDS unpadded (required by global_load_lds wave-uniform-base semantics).
// Requirements: M multiple of 128 (per m0), staged W rows n0..n0+127 readable, K % 32 == 0.
using bf16x8 = __attribute__((ext_vector_type(8))) short;
using f32x4  = __attribute__((ext_vector_type(4))) float;

__device__ __forceinline__ void gldl16(const void* g, void* l) {
    __builtin_amdgcn_global_load_lds(
        (const __attribute__((address_space(1))) unsigned int*)g,
        (__attribute__((address_space(3))) unsigned int*)l, 16, 0, 0);
}

__device__ __forceinline__ void gemm_mfma_body(
    const u16* __restrict__ A, const u16* __restrict__ W,
    const float* __restrict__ bias, float* __restrict__ C,
    int Kd, int lda, int ldw, int ldc, int nmax, int m0, int n0)
{
    __shared__ __align__(16) u16 As[128 * 32];
    __shared__ __align__(16) u16 Ws[128 * 32];
    const int tid = threadIdx.x;
    const int lane = tid & 63;
    const int wave = tid >> 6;
    const int wm = (wave & 1) << 6, wn = (wave >> 1) << 6;
    const int fr = lane & 15, fk = lane >> 4;      // fragment row / k-chunk
    f32x4 acc[4][4] = {};

    // staging: thread e covers global row (e>>2), 16B k-chunk (e&3); LDS offset e*16B
    const int sr = tid >> 2, sk = (tid & 3) << 3;
    const u16* ga0 = A + (size_t)(m0 + sr) * lda + sk;
    const u16* ga1 = ga0 + (size_t)64 * lda;
    const u16* gw0 = W + (size_t)(n0 + sr) * ldw + sk;
    const u16* gw1 = gw0 + (size_t)64 * ldw;
    u16* la0 = As + tid * 8;
    u16* la1 = la0 + 2048;
    u16* lw0 = Ws + tid * 8;
    u16* lw1 = lw0 + 2048;

    for (int k0 = 0; k0 < Kd; k0 += 32) {
        gldl16(ga0 + k0, la0);
        gldl16(ga1 + k0, la1);
        gldl16(gw0 + k0, lw0);
        gldl16(gw1 + k0, lw1);
        __syncthreads();
        bf16x8 af[4], wf[4];
#pragma unroll
        for (int i = 0; i < 4; ++i)
            af[i] = *reinterpret_cast<const bf16x8*>(&As[(wm + i * 16 + fr) * 32 + fk * 8]);
#pragma unroll
        for (int j = 0; j < 4; ++j)
            wf[j] = *reinterpret_cast<const bf16x8*>(&Ws[(wn + j * 16 + fr) * 32 + fk * 8]);
#pragma unroll
        for (int i = 0; i < 4; ++i)
#pragma unroll
            for (int j = 0; j < 4; ++j)
                acc[i][j] = __builtin_amdgcn_mfma_f32_16x16x32_bf16(af[i], wf[j], acc[i][j], 0, 0, 0);
        __syncthreads();
    }

    // C/D layout (m89-verified): col = lane&15, row = (lane>>4)*4 + reg
    const int cr = (lane >> 4) << 2, cc = lane & 15;
#pragma unroll
    for (int j = 0; j < 4; ++j) {
        int n = n0 + wn + j * 16 + cc;
        if (n < nmax) {
            float bv = bias ? bias[n] : 0.f;
#pragma unroll
            for (int i = 0; i < 4; ++i) {
                int m = m0 + wm + i * 16 + cr;
                float* cp = C + (size_t)m * ldc + n;
#pragma unroll
                for (int r = 0; r < 4; ++r)
                    cp[(size_t)r * ldc] = acc[i][j][r] + bv;
            }
        }
    }
}

__global__ __launch_bounds__(256) void gemm_bf16_k(
    const u16* __restrict__ A, const u16* __restrict__ W,
    const float* __restrict__ bias, float* __restrict__ C,
    int Kd, int lda, int ldw, int ldc, int nmax)
{
    gemm_mfma_body(A, W, bias, C, Kd, lda, ldw, ldc, nmax,
                   blockIdx.x * 128, blockIdx.y * 128);
}

// Encoder recurrent GEMM, both directions via blockIdx.z. g layout: [dir][512][2048]
__global__ __launch_bounds__(256) void gemm_enc_mfma(
    const u16* __restrict__ hF, const u16* __restrict__ hB,
    const u16* __restrict__ Wf, const u16* __restrict__ Wb,
    float* __restrict__ g)
{
    const u16* A = blockIdx.z ? hB : hF;
    const u16* W = blockIdx.z ? Wb : Wf;
    float* C = g + (size_t)blockIdx.z * ((size_t)B_ * 4 * HE_);
    gemm_mfma_body(A, W, nullptr, C, HE_, HE_, HE_, 4 * HE_, 4 * HE_,
                   blockIdx.x * 128, blockIdx.y * 128);
}

// ================= fp32 tiled GEMM (kept for small latent GEMMs) =================
__device__ __forceinline__ void gemm_body(
    const float* __restrict__ A, const float* __restrict__ W,
    const float* __restrict__ bias, float* __restrict__ C,
    int N, int Kd, int lda, int aoff, int ldw, int woff,
    int ldc, int coff, int m0, int n0)
{
    __shared__ __align__(16) float As[16][68];
    __shared__ __align__(16) float Ws[16][68];
    const int tid = threadIdx.x;
    const int tx = tid & 15, ty = tid >> 4;
    float acc[4][4] = {};
    for (int k0 = 0; k0 < Kd; k0 += 16) {
#pragma unroll
        for (int i = 0; i < 4; ++i) {
            int e = tid + i * 256;
            int mm = e >> 4, kk = e & 15;
            As[kk][mm] = A[(size_t)(m0 + mm) * lda + aoff + k0 + kk];
        }
#pragma unroll
        for (int i = 0; i < 4; ++i) {
            int e = tid + i * 256;
            int nn = e >> 4, kk = e & 15;
            int n = n0 + nn;
            Ws[kk][nn] = (n < N) ? W[(size_t)n * ldw + woff + k0 + kk] : 0.f;
        }
        __syncthreads();
#pragma unroll
        for (int kk = 0; kk < 16; ++kk) {
            float4 a = *reinterpret_cast<const float4*>(&As[kk][ty * 4]);
            float4 w = *reinterpret_cast<const float4*>(&Ws[kk][tx * 4]);
            float av[4] = {a.x, a.y, a.z, a.w};
            float wv[4] = {w.x, w.y, w.z, w.w};
#pragma unroll
            for (int i = 0; i < 4; ++i)
#pragma unroll
                for (int j = 0; j < 4; ++j)
                    acc[i][j] = fmaf(av[i], wv[j], acc[i][j]);
        }
        __syncthreads();
    }
#pragma unroll
    for (int i = 0; i < 4; ++i) {
        int m = m0 + ty * 4 + i;
#pragma unroll
        for (int j = 0; j < 4; ++j) {
            int n = n0 + tx * 4 + j;
            if (n < N) {
                float v = acc[i][j];
                if (bias) v += bias[n];
                C[(size_t)m * ldc + coff + n] = v;
            }
        }
    }
}

__global__ __launch_bounds__(256) void gemm_k(
    const float* __restrict__ A, const float* __restrict__ W,
    const float* __restrict__ bias, float* __restrict__ C,
    int N, int Kd, int lda, int aoff, int ldw, int woff, int ldc, int coff)
{
    gemm_body(A, W, bias, C, N, Kd, lda, aoff, ldw, woff, ldc, coff,
              blockIdx.x * 64, blockIdx.y * 64);
}

// ================= conversion kernels =================
__global__ __launch_bounds__(256) void conv_bf16(
    const float* __restrict__ src, u16* __restrict__ dst, int n)
{
    int stride = gridDim.x * 256;
    for (int i = blockIdx.x * 256 + threadIdx.x; i < n; i += stride)
        dst[i] = f2bf(src[i]);
}

__global__ __launch_bounds__(256) void conv_outw(
    const float* __restrict__ w, u16* __restrict__ dst)
{
    int i = blockIdx.x * 256 + threadIdx.x;   // 128*2048
    int row = i >> 11, col = i & 2047;
    dst[i] = (row < NOUT_) ? f2bf(w[(size_t)row * HD_ + col]) : (u16)0;
}

// ================= pointwise kernels =================
__global__ __launch_bounds__(256) void point_enc(
    const float* __restrict__ g, const float* __restrict__ data,
    const float* __restrict__ Wih_f, const float* __restrict__ bf,
    const float* __restrict__ Wih_b, const float* __restrict__ bb,
    const int* __restrict__ lengths,
    float* __restrict__ hF, float* __restrict__ cF,
    float* __restrict__ hB, float* __restrict__ cB,
    u16* __restrict__ hFb, u16* __restrict__ hBb, int t)
{
    int idx = blockIdx.x * 256 + threadIdx.x;   // 2*512*512
    int dir = idx >> 18;
    int r = idx & ((1 << 18) - 1);
    int b = r >> 9, n = r & 511;
    int L = lengths[b]; L = L < 1 ? 1 : (L > 128 ? 128 : L);
    if (t >= L) return;  // masked step: h,c unchanged
    const float* gp = g + (size_t)dir * ((size_t)B_ * 4 * HE_) + (size_t)b * (4 * HE_);
    float gi = gp[n], gf = gp[HE_ + n], gg = gp[2 * HE_ + n], go = gp[3 * HE_ + n];
    int row = dir ? (L - 1 - t) : t;
    float x0 = data[b * 258 + (row + 1) * 2 + 0];
    float x1 = data[b * 258 + (row + 1) * 2 + 1];
    const float* Wih = dir ? Wih_b : Wih_f;
    const float* bias = dir ? bb : bf;
    gi += bias[n]          + x0 * Wih[2 * n]              + x1 * Wih[2 * n + 1];
    gf += bias[HE_ + n]    + x0 * Wih[2 * (HE_ + n)]      + x1 * Wih[2 * (HE_ + n) + 1];
    gg += bias[2*HE_ + n]  + x0 * Wih[2 * (2*HE_ + n)]    + x1 * Wih[2 * (2*HE_ + n) + 1];
    go += bias[3*HE_ + n]  + x0 * Wih[2 * (3*HE_ + n)]    + x1 * Wih[2 * (3*HE_ + n) + 1];
    float* h = dir ? hB : hF;
    float* c = dir ? cB : cF;
    u16* hb = dir ? hBb : hFb;
    int o = b * HE_ + n;
    float c2 = sigm(gf) * c[o] + sigm(gi) * tanhf(gg);
    float h2 = sigm(go) * tanhf(c2);
    h[o] = h2; c[o] = c2; hb[o] = f2bf(h2);
}

__global__ __launch_bounds__(256) void copy_hn(
    const float* __restrict__ hF, const float* __restrict__ hB, float* __restrict__ hn)
{
    int i = blockIdx.x * 256 + threadIdx.x;   // 512*1024
    int b = i >> 10, j = i & 1023;
    hn[i] = (j < 512) ? hF[b * 512 + j] : hB[b * 512 + j - 512];
}

__global__ __launch_bounds__(256) void point_z(
    const float* __restrict__ zmzl, const float* __restrict__ eps,
    float* __restrict__ ozm, float* __restrict__ ozl, float* __restrict__ z)
{
    int i = blockIdx.x * 256 + threadIdx.x;   // 512*128
    int b = i >> 7, j = i & 127;
    float zm = zmzl[b * 256 + j], zl = zmzl[b * 256 + 128 + j];
    ozm[i] = zm; ozl[i] = zl;
    z[i] = zm + expf(0.5f * zl) * eps[i];
}

__global__ __launch_bounds__(256) void point_init(
    const float* __restrict__ g, float* __restrict__ h, float* __restrict__ c,
    u16* __restrict__ hb)
{
    int i = blockIdx.x * 256 + threadIdx.x;   // 512*2048
    int b = i >> 11, n = i & 2047;
    float hv = tanhf(g[(size_t)b * 4096 + n]);
    h[i] = hv; hb[i] = f2bf(hv);
    c[i] = tanhf(g[(size_t)b * 4096 + 2048 + n]);
}

__global__ __launch_bounds__(256) void prep_wx(
    const float* __restrict__ Wih, float* __restrict__ wx)
{
    int j = blockIdx.x * 256 + threadIdx.x;   // 8192
    wx[j] = Wih[(size_t)j * 133];
    wx[8192 + j] = Wih[(size_t)j * 133 + 1];
}

__global__ __launch_bounds__(256) void point_dec(
    const float* __restrict__ g, const float* __restrict__ zW,
    const float* __restrict__ data, const float* __restrict__ wx,
    float* __restrict__ h, float* __restrict__ c,
    u16* __restrict__ hb, u16* __restrict__ hs, int t)
{
    int idx = blockIdx.x * 256 + threadIdx.x;  // 512*2048
    int b = idx >> 11, n = idx & 2047;
    float x0 = data[b * 258 + t * 2 + 0];
    float x1 = data[b * 258 + t * 2 + 1];
    const float* gp = g + (size_t)b * 8192;
    const float* zp = zW + (size_t)b * 8192;
    int j0 = n, j1 = 2048 + n, j2 = 4096 + n, j3 = 6144 + n;
    float gi = gp[j0] + zp[j0] + x0 * wx[j0] + x1 * wx[8192 + j0];
    float gf = gp[j1] + zp[j1] + x0 * wx[j1] + x1 * wx[8192 + j1];
    float gg = gp[j2] + zp[j2] + x0 * wx[j2] + x1 * wx[8192 + j2];
    float go = gp[j3] + zp[j3] + x0 * wx[j3] + x1 * wx[8192 + j3];
    float c2 = sigm(gf) * c[idx] + sigm(gi) * tanhf(gg);
    float h2 = sigm(go) * tanhf(c2);
    h[idx] = h2; c[idx] = c2;
    u16 hv = f2bf(h2);
    hb[idx] = hv;
    if (hs) hs[(size_t)b * (T_ * HD_) + (size_t)t * HD_ + n] = hv;
}

// Per-step output projection fallback (fp32): params[b,t,:] = h[b,:] @ out_W^T + out_b
__global__ __launch_bounds__(256) void proj_step(
    const float* __restrict__ h, const float* __restrict__ out_W,
    const float* __restrict__ out_b, float* __restrict__ out, int t)
{
    __shared__ __align__(16) float sh[2048];
    int b = blockIdx.x;
    for (int i = threadIdx.x; i < 2048; i += 256) sh[i] = h[(size_t)b * 2048 + i];
    __syncthreads();
    int n = threadIdx.x >> 1, half = threadIdx.x & 1;
    if (n >= NOUT_) return;
    const float4* w4 = reinterpret_cast<const float4*>(out_W + (size_t)n * 2048 + half * 1024);
    const float4* h4 = reinterpret_cast<const float4*>(sh + half * 1024);
    float s = 0.f;
#pragma unroll 4
    for (int k = 0; k < 256; ++k) {
        float4 a = h4[k], w = w4[k];
        s += a.x * w.x + a.y * w.y + a.z * w.z + a.w * w.w;
    }
    s += __shfl_xor(s, 1);
    if (half == 0) out[(size_t)b * (T_ * NOUT_) + (size_t)t * NOUT_ + n] = s + out_b[n];
}

extern "C" void kernel_launch(void* const* d_in, const int* in_sizes, int n_in,
                              void* d_out, int out_size, void* d_ws, size_t ws_size,
                              hipStream_t stream)
{
    const float* data      = (const float*)d_in[0];
    const float* eps       = (const float*)d_in[1];
    const float* enc_Wih_f = (const float*)d_in[2];
    const float* enc_Whh_f = (const float*)d_in[3];
    const float* enc_b_f   = (const float*)d_in[4];
    const float* enc_Wih_b = (const float*)d_in[5];
    const float* enc_Whh_b = (const float*)d_in[6];
    const float* enc_b_b   = (const float*)d_in[7];
    const float* enc_out_W = (const float*)d_in[8];
    const float* enc_out_b = (const float*)d_in[9];
    const float* init_W    = (const float*)d_in[10];
    const float* init_b    = (const float*)d_in[11];
    const float* dec_Wih   = (const float*)d_in[12];
    const float* dec_Whh   = (const float*)d_in[13];
    const float* dec_b     = (const float*)d_in[14];
    const float* out_W     = (const float*)d_in[15];
    const float* out_b     = (const float*)d_in[16];
    const int*   lengths   = (const int*)d_in[17];

    float* ws  = (float*)d_ws;
    float* out = (float*)d_out;
    float* hF = ws + OFF_HF, *cF = ws + OFF_CF, *hB = ws + OFF_HB, *cB = ws + OFF_CB;
    float* hd = ws + OFF_HD, *cd = ws + OFF_CD;
    float* zW = ws + OFF_ZW, *g = ws + OFF_G, *hn = ws + OFF_HN;
    float* zmzl = ws + OFF_ZMZL, *z = ws + OFF_Z, *wx = ws + OFF_WX;
    u16* bw = (u16*)(ws + BASE_FLOATS);
    u16* wbDec = bw + SH_WDEC, *wbEncF = bw + SH_WENCF, *wbEncB = bw + SH_WENCB;
    u16* wbOut = bw + SH_OUTW;
    u16* hbDec = bw + SH_HDEC, *hbEncF = bw + SH_HENCF, *hbEncB = bw + SH_HENCB;
    float* ozm = out + (size_t)B_ * T_ * NOUT_;
    float* ozl = ozm + (size_t)B_ * Z_;

    // weight conversions (every call: ws is re-poisoned)
    conv_bf16<<<4096, 256, 0, stream>>>(dec_Whh, wbDec, 4 * HD_ * HD_);
    conv_bf16<<<1024, 256, 0, stream>>>(enc_Whh_f, wbEncF, 4 * HE_ * HE_);
    conv_bf16<<<1024, 256, 0, stream>>>(enc_Whh_b, wbEncB, 4 * HE_ * HE_);
    conv_outw<<<1024, 256, 0, stream>>>(out_W, wbOut);

    // zero-init encoder h/c (fp32) and bf16 h (F and B contiguous)
    hipMemsetAsync(ws, 0, (size_t)4 * B_ * HE_ * sizeof(float), stream);
    hipMemsetAsync(hbEncF, 0, (size_t)2 * B_ * HE_ * sizeof(u16), stream);

    // ---- encoder: 128 steps, both directions fused per launch
    for (int t = 0; t < T_; ++t) {
        gemm_enc_mfma<<<dim3(4, 16, 2), 256, 0, stream>>>(hbEncF, hbEncB, wbEncF, wbEncB, g);
        point_enc<<<2048, 256, 0, stream>>>(g, data, enc_Wih_f, enc_b_f, enc_Wih_b, enc_b_b,
                                            lengths, hF, cF, hB, cB, hbEncF, hbEncB, t);
    }

    // ---- latent + decoder init (fp32, tiny)
    copy_hn<<<2048, 256, 0, stream>>>(hF, hB, hn);
    gemm_k<<<dim3(8, 4), 256, 0, stream>>>(hn, enc_out_W, enc_out_b, zmzl,
                                           256, 1024, 1024, 0, 1024, 0, 256, 0);
    point_z<<<256, 256, 0, stream>>>(zmzl, eps, ozm, ozl, z);
    gemm_k<<<dim3(8, 64), 256, 0, stream>>>(z, init_W, init_b, g,
                                            4096, 128, 128, 0, 128, 0, 4096, 0);
    point_init<<<4096, 256, 0, stream>>>(g, hd, cd, hbDec);
    gemm_k<<<dim3(8, 128), 256, 0, stream>>>(z, dec_Wih, dec_b, zW,
                                             8192, 128, 128, 0, 133, 5, 8192, 0);
    prep_wx<<<32, 256, 0, stream>>>(dec_Wih, wx);

    // ---- decoder: 128 steps (bf16 MFMA recurrent GEMM)
    bool big = ws_size >= BASE_FLOATS * sizeof(float) + (SH_HS + HS_SHORTS) * sizeof(u16);
    u16* hs = big ? (bw + SH_HS) : nullptr;
    for (int t = 0; t < T_; ++t) {
        gemm_bf16_k<<<dim3(4, 64), 256, 0, stream>>>(hbDec, wbDec, nullptr, g,
                                                     2048, 2048, 2048, 8192, 8192);
        point_dec<<<4096, 256, 0, stream>>>(g, zW, data, wx, hd, cd, hbDec, hs, t);
        if (!big) proj_step<<<512, 256, 0, stream>>>(hd, out_W, out_b, out, t);
    }
    if (big) {
        // params = hs @ out_W^T + out_b  (M=65536, N=123 padded to 128, K=2048)
        gemm_bf16_k<<<dim3(512, 1), 256, 0, stream>>>(hs, wbOut, out_b, out,
                                                      2048, 2048, 2048, 123, 123);
    }
}